// Round 25
// baseline (335.995 us; speedup 1.0000x reference)
//
#include <hip/hip_runtime.h>
#include <math.h>

#define TT   256   // timesteps
#define HH   64    // hidden
#define INw  46    // input size
#define NCLS 8     // classes
#define BB   8     // batch rows per scan block (grid 256)
#define CH   2     // timesteps per chunk (small -> LDS 42 KB -> 2 blocks/CU)
#define NCH  (TT / CH)
#define B2   8     // batch rows per epilogue block
#define XS   80    // short stride for x/h LDS rows (160B -> 2-way free aliasing)

typedef __attribute__((ext_vector_type(8))) short  short8v;  // 8 bf16
typedef __attribute__((ext_vector_type(4))) float  float4v;

__device__ __forceinline__ float frcp(float x) { return __builtin_amdgcn_rcpf(x); }
__device__ __forceinline__ float sigmoid_f(float x) { return frcp(1.f + __expf(-x)); }
__device__ __forceinline__ float tanh_f(float x) {
    float a = fabsf(x);
    float e = __expf(-2.f * a);
    float r = (1.f - e) * frcp(1.f + e);
    return x >= 0.f ? r : -r;
}
__device__ __forceinline__ float dot4(float4 w, float4 a, float acc) {
    acc = fmaf(w.x, a.x, acc);
    acc = fmaf(w.y, a.y, acc);
    acc = fmaf(w.z, a.z, acc);
    acc = fmaf(w.w, a.w, acc);
    return acc;
}

// float -> bf16 round-to-nearest-even
__device__ __forceinline__ unsigned short f2bf(float f) {
    unsigned int u = __float_as_uint(f);
    unsigned int r = u + 0x7FFFu + ((u >> 16) & 1u);
    return (unsigned short)(r >> 16);
}
__device__ __forceinline__ float bf2f(unsigned short h) {
    return __uint_as_float(((unsigned int)h) << 16);
}
__device__ __forceinline__ void split8(const float v[8], short8v& hi, short8v& lo) {
#pragma unroll
    for (int e = 0; e < 8; ++e) {
        unsigned short h = f2bf(v[e]);
        hi[e] = (short)h;
        lo[e] = (short)f2bf(v[e] - bf2f(h));
    }
}

#define MFMA16(A,B,C) __builtin_amdgcn_mfma_f32_16x16x32_bf16((A),(B),(C),0,0,0)

// ---------------------------------------------------------------------------
// In-lane MFMA LSTM scan, ONE barrier/step, 8-wave blocks, 2 blocks/CU (R25).
// R24's co-residency failed on (a) LDS 80.9KB x2 with zero slack and (b)
// spill from fat P-waves under the forced 128-reg cap. Fixes:
//   CH=2 -> zx[2][2][4][64][8] = 32 KB, total LDS ~42 KB (x2 = 84 KB, slack);
//   producer = ONE 24-MFMA burst per chunk (A-tile = 2 ts x 8 rows, all 16
//   A-rows distinct: trel=c16>>3, rr=c16&7, tout=g>>1), slim registers
//   (3 held loads, R23 profile).
//   waves 0-3 (C): ALL four gate tiles in-lane -> 24 MFMA/step, aliased-lane
//                  split (g-group owns 2 batch rows), update, h hi+lo write.
//                  (R23-verbatim math)
//   waves 4-7 (P): s0 stage-write x[c+1]; s1 burst(nb) + issue loads x[c+2].
// __launch_bounds__(512,4): two blocks co-reside -> 4 waves/SIMD; block A's
// chain stalls filled by block B's independent recurrence; 8-wave barriers.
// 3-term split-bf16, fp32 accumulate; bit-identical per-accumulator order.
// ---------------------------------------------------------------------------
__global__ __launch_bounds__(512, 4) void lstm_fwd_mfma(
    const float* __restrict__ x,     // (B,T,46)
    const float* __restrict__ Wih,   // (256,46)
    const float* __restrict__ Whh,   // (256,64)
    const float* __restrict__ bih,   // (256)
    const float* __restrict__ bhh,   // (256)
    float* __restrict__ hf_out)      // (B,64)
{
    __shared__ float zx[2][CH][4][HH][8];    // 32 KB (chunk-parity dbuf)
    __shared__ short x_hi[CH][BB][XS];       // 2.5 KB (single buffer)
    __shared__ short x_lo[CH][BB][XS];       // 2.5 KB
    __shared__ short h_hi[2][BB][XS];        // 2.5 KB (step-parity dbuf)
    __shared__ short h_lo[2][BB][XS];        // 2.5 KB

    const int j    = threadIdx.x;
    const int w    = j >> 6;
    const int l    = j & 63;
    const int g    = l >> 4;
    const int c16  = l & 15;
    const int b0   = blockIdx.x * BB;
    const int wl   = w & 3;
    const int u    = 16 * wl + c16;
    const int r0p  = ((g & 1) * 4) ^ (u & 4);
    const bool isC  = (w < 4);
    const bool isP  = !isC;
    // aliased-lane split: this lane's 2 batch rows and matching C-reg offset
    const bool hi2  = (g & 2) != 0;          // use regs 2,3 instead of 0,1
    const int  row0 = 4 * (g & 1) + 2 * (g >> 1);   // first owned batch row

    // ---- weight fragments ----
    // consumers: wf[q]=Whh_hi, wf[4+q]=Whh_lo (q = gate 0..3)
    // producers: wf[q]=Wih_hi, wf[4+q]=Wih_lo (q = gate 0..3)
    short8v wf[8][2];
    float bias4[4] = {0.f, 0.f, 0.f, 0.f};
    if (isC) {
#pragma unroll
        for (int q = 0; q < 4; ++q) {
            const int n = 64 * q + u;
            bias4[q] = bih[n] + bhh[n];
#pragma unroll
            for (int s2 = 0; s2 < 2; ++s2) {
                float vh[8];
#pragma unroll
                for (int e = 0; e < 8; ++e)
                    vh[e] = Whh[n * HH + 32 * s2 + 8 * g + e];
                split8(vh, wf[q][s2], wf[4 + q][s2]);
            }
        }
    } else {
#pragma unroll
        for (int q = 0; q < 4; ++q) {
            const int n = 64 * q + u;
#pragma unroll
            for (int s2 = 0; s2 < 2; ++s2) {
                float vi[8];
#pragma unroll
                for (int e = 0; e < 8; ++e) {
                    const int k = 32 * s2 + 8 * g + e;
                    const float tval = Wih[n * INw + ((k < INw) ? k : 0)];
                    vi[e] = (k < INw) ? tval : 0.f;
                }
                split8(vi, wf[q][s2], wf[4 + q][s2]);
            }
        }
    }

    // ---- zero h bufs and x bufs (incl. k>=46 pad; staging writes only k<46,
    //      pad stays zero across all chunks) ----
    {
        short* hh0 = &h_hi[0][0][0];
        short* hl0 = &h_lo[0][0][0];
        for (int idx = j; idx < 2 * BB * XS; idx += 512) {
            hh0[idx] = 0;
            hl0[idx] = 0;
        }
        short* xh0 = &x_hi[0][0][0];
        short* xl0 = &x_lo[0][0][0];
        for (int idx = j; idx < CH * BB * XS; idx += 512) {
            xh0[idx] = 0;
            xl0[idx] = 0;
        }
    }
    __syncthreads();

    // ---- stage x chunk 0 (all threads; 736 elements) ----
    for (int e = j; e < BB * CH * INw; e += 512) {
        const int r   = e / (CH * INw);
        const int rem = e - r * (CH * INw);
        const int tt  = rem / INw;
        const int k   = rem - tt * INw;
        const float v = x[((size_t)(b0 + r) * TT + tt) * INw + k];
        const unsigned short hh = f2bf(v);
        x_hi[tt][r][k] = (short)hh;
        x_lo[tt][r][k] = (short)f2bf(v - bf2f(hh));
    }
    __syncthreads();

    // zx producer burst: ONE per chunk, all 4 gates, covers both timesteps
    // (A-row a = c16: timestep a>>3, batch row a&7; D rows 4g+r -> tout=g>>1)
    auto zx_burst = [&](int nbuf) {
        const int trel = c16 >> 3;
        const int rr   = c16 & 7;
        const short* ph = &x_hi[trel][rr][0] + 8 * g;
        const short* pl = &x_lo[trel][rr][0] + 8 * g;
        const short8v axh0 = *(const short8v*)(ph);
        const short8v axh1 = *(const short8v*)(ph + 32);
        const short8v axl0 = *(const short8v*)(pl);
        const short8v axl1 = *(const short8v*)(pl + 32);
        const int tout = g >> 1;
#pragma unroll
        for (int q = 0; q < 4; ++q) {
            float4v C = {0.f, 0.f, 0.f, 0.f};
            C = MFMA16(axh0, wf[q][0], C);
            C = MFMA16(axh1, wf[q][1], C);
            C = MFMA16(axh0, wf[4 + q][0], C);
            C = MFMA16(axh1, wf[4 + q][1], C);
            C = MFMA16(axl0, wf[q][0], C);
            C = MFMA16(axl1, wf[q][1], C);
            *(float4v*)&zx[nbuf][tout][q][u][r0p] = C;
        }
    };

    // staging offsets (P lanes: j-256 in [0,256); 736 elems -> 3 slots)
    size_t st_gof[3]; int st_lds[3]; bool st_ok[3];
#pragma unroll
    for (int it = 0; it < 3; ++it) {
        const int e  = (j - 256) + 256 * it;
        const bool ok = (e >= 0) && (e < BB * CH * INw);
        const int ec = ok ? e : 0;
        const int r   = ec / (CH * INw);
        const int rem = ec - r * (CH * INw);
        const int tt  = rem / INw;
        const int k   = rem - tt * INw;
        st_ok[it]  = ok;
        st_gof[it] = ((size_t)(b0 + r) * TT + tt) * INw + k;
        st_lds[it] = (tt * BB + r) * XS + k;
    }
    short* xsh = &x_hi[0][0][0];
    short* xsl = &x_lo[0][0][0];

    // ---- prologue: zx[0] (producers) + issue global loads for chunk 1 ----
    float xhold[3];
    if (isP) {
        zx_burst(0);
#pragma unroll
        for (int it = 0; it < 3; ++it)
            if (st_ok[it]) xhold[it] = x[st_gof[it] + (size_t)(CH * INw)];
    }

    float cst2[2]  = {0.f, 0.f};   // cell state for this lane's 2 rows
    float hnew2[2] = {0.f, 0.f};
    __syncthreads();

    for (int c = 0; c < NCH; ++c) {
        const int cb = c & 1, nb = cb ^ 1;
#pragma unroll
        for (int s = 0; s < CH; ++s) {
            const int t = c * CH + s;
            // ============ single phase: all work, then ONE barrier =========
            if (isC) {
                const short* hrh = &h_hi[(t + 1) & 1][0][0];
                const short* hrl = &h_lo[(t + 1) & 1][0][0];
                const int ro = (c16 & 7) * XS;
                const short8v ahh0 = *(const short8v*)(hrh + ro + 8 * g);
                const short8v ahh1 = *(const short8v*)(hrh + ro + 32 + 8 * g);
                const short8v ahl0 = *(const short8v*)(hrl + ro + 8 * g);
                const short8v ahl1 = *(const short8v*)(hrl + ro + 32 + 8 * g);
                const float* zr = &zx[cb][s][0][u][r0p];
                float4v C0 = *(const float4v*)(zr);
                float4v C1 = *(const float4v*)(zr + 512);
                float4v C2 = *(const float4v*)(zr + 1024);
                float4v C3 = *(const float4v*)(zr + 1536);
                float4v D0 = {0.f, 0.f, 0.f, 0.f};
                float4v D1 = {0.f, 0.f, 0.f, 0.f};
                __builtin_amdgcn_s_setprio(1);
                // gates 0,1 (i,f)
                C0 = MFMA16(ahh0, wf[0][0], C0);
                C1 = MFMA16(ahh0, wf[1][0], C1);
                D0 = MFMA16(ahl0, wf[0][0], D0);
                D1 = MFMA16(ahl0, wf[1][0], D1);
                C0 = MFMA16(ahh1, wf[0][1], C0);
                C1 = MFMA16(ahh1, wf[1][1], C1);
                D0 = MFMA16(ahl1, wf[0][1], D0);
                D1 = MFMA16(ahl1, wf[1][1], D1);
                D0 = MFMA16(ahh0, wf[4][0], D0);
                D1 = MFMA16(ahh0, wf[5][0], D1);
                D0 = MFMA16(ahh1, wf[4][1], D0);
                D1 = MFMA16(ahh1, wf[5][1], D1);
                C0 += D0;
                C1 += D1;
                // gates 2,3 (g,o)
                float4v E0 = {0.f, 0.f, 0.f, 0.f};
                float4v E1 = {0.f, 0.f, 0.f, 0.f};
                C2 = MFMA16(ahh0, wf[2][0], C2);
                C3 = MFMA16(ahh0, wf[3][0], C3);
                E0 = MFMA16(ahl0, wf[2][0], E0);
                E1 = MFMA16(ahl0, wf[3][0], E1);
                C2 = MFMA16(ahh1, wf[2][1], C2);
                C3 = MFMA16(ahh1, wf[3][1], C3);
                E0 = MFMA16(ahl1, wf[2][1], E0);
                E1 = MFMA16(ahl1, wf[3][1], E1);
                E0 = MFMA16(ahh0, wf[6][0], E0);
                E1 = MFMA16(ahh0, wf[7][0], E1);
                E0 = MFMA16(ahh1, wf[6][1], E0);
                E1 = MFMA16(ahh1, wf[7][1], E1);
                __builtin_amdgcn_s_setprio(0);
                C2 += E0;
                C3 += E1;
                // in-lane update for MY 2 rows
                const int ri = hi2 ? 2 : 0;
#pragma unroll
                for (int rr = 0; rr < 2; ++rr) {
                    const float iv = sigmoid_f(C0[ri + rr] + bias4[0]);
                    const float fv = sigmoid_f(C1[ri + rr] + bias4[1]);
                    const float gv = tanh_f   (C2[ri + rr] + bias4[2]);
                    const float ov = sigmoid_f(C3[ri + rr] + bias4[3]);
                    cst2[rr]  = fmaf(fv, cst2[rr], iv * gv);
                    hnew2[rr] = ov * tanh_f(cst2[rr]);
                }
                short* hwh = &h_hi[t & 1][0][0] + row0 * XS + u;
                short* hwl = &h_lo[t & 1][0][0] + row0 * XS + u;
                const unsigned short h0h = f2bf(hnew2[0]);
                hwh[0]  = (short)h0h;
                hwl[0]  = (short)f2bf(hnew2[0] - bf2f(h0h));
                const unsigned short h1h = f2bf(hnew2[1]);
                hwh[XS] = (short)h1h;
                hwl[XS] = (short)f2bf(hnew2[1] - bf2f(h1h));
            } else {
                if (s == 0 && c + 1 < NCH) {
                    // write held x for chunk c+1 (loads issued at (c-1, s1))
#pragma unroll
                    for (int it = 0; it < 3; ++it) {
                        if (st_ok[it]) {
                            const unsigned short hh = f2bf(xhold[it]);
                            xsh[st_lds[it]] = (short)hh;
                            xsl[st_lds[it]] = (short)f2bf(xhold[it] - bf2f(hh));
                        }
                    }
                } else if (s == 1) {
                    if (c + 1 < NCH) zx_burst(nb);
                    if (c + 2 < NCH) {
                        const size_t cofs = (size_t)(c + 2) * (CH * INw);
#pragma unroll
                        for (int it = 0; it < 3; ++it)
                            if (st_ok[it]) xhold[it] = x[st_gof[it] + cofs];
                    }
                }
            }
            __syncthreads();   // THE one barrier per step
        }
    }

    if (isC) {
        hf_out[(size_t)(b0 + row0)     * HH + u] = hnew2[0];
        hf_out[(size_t)(b0 + row0 + 1) * HH + u] = hnew2[1];
    }
}

// ---------------------------------------------------------------------------
// Epilogue: backward dir = ONE LSTM step on x[:,T-1,:] (h0=c0=0, Whh_b unused),
// then FC + softmax.
// ---------------------------------------------------------------------------
__global__ __launch_bounds__(256) void lstm_bwd_fc(
    const float* __restrict__ x,
    const float* __restrict__ Wih,
    const float* __restrict__ bih,
    const float* __restrict__ bhh,
    const float* __restrict__ fcW,
    const float* __restrict__ fcb,
    const float* __restrict__ hf,
    float* __restrict__ out)
{
    __shared__ float xl[B2][48];
    __shared__ float act[B2][256];
    __shared__ float hbl[B2][HH];

    const int j  = threadIdx.x;
    const int b0 = blockIdx.x * B2;

    for (int e = j; e < B2 * INw; e += 256) {
        int b = e / INw, i = e - b * INw;
        xl[b][i] = x[((size_t)(b0 + b) * TT + (TT - 1)) * INw + i];
    }
    if (j < B2) { xl[j][46] = 0.f; xl[j][47] = 0.f; }
    __syncthreads();

    float4 wih4[12];
#pragma unroll
    for (int ii = 0; ii < 11; ++ii)
        wih4[ii] = make_float4(Wih[j*INw + 4*ii + 0], Wih[j*INw + 4*ii + 1],
                               Wih[j*INw + 4*ii + 2], Wih[j*INw + 4*ii + 3]);
    wih4[11] = make_float4(Wih[j*INw + 44], Wih[j*INw + 45], 0.f, 0.f);
    const float bias = bih[j] + bhh[j];
    const bool  gate_is_tanh = ((j >> 6) == 2);

#pragma unroll
    for (int b = 0; b < B2; ++b) {
        float a = bias;
#pragma unroll
        for (int ii = 0; ii < 12; ++ii) {
            float4 xv = *(const float4*)&xl[b][4*ii];
            a = dot4(wih4[ii], xv, a);
        }
        act[b][j] = gate_is_tanh ? tanh_f(a) : sigmoid_f(a);
    }
    __syncthreads();

    for (int q = j; q < B2 * HH; q += 256) {
        int b = q >> 6, ll = q & 63;
        float ig = act[b][ll];
        float gg = act[b][128 + ll];
        float og = act[b][192 + ll];
        hbl[b][ll] = og * tanh_f(ig * gg);
    }
    __syncthreads();

    if (j < B2 * NCLS) {
        int b = j >> 3, n = j & 7;
        float a = fcb[n];
        const float* hfr = hf + (size_t)(b0 + b) * HH;
#pragma unroll
        for (int ll = 0; ll < HH; ++ll) {
            a = fmaf(fcW[n * 2 * HH + ll],      hfr[ll],    a);
            a = fmaf(fcW[n * 2 * HH + HH + ll], hbl[b][ll], a);
        }
        float m = a;
        m = fmaxf(m, __shfl_xor(m, 1, 8));
        m = fmaxf(m, __shfl_xor(m, 2, 8));
        m = fmaxf(m, __shfl_xor(m, 4, 8));
        float e = __expf(a - m);
        float s = e;
        s += __shfl_xor(s, 1, 8);
        s += __shfl_xor(s, 2, 8);
        s += __shfl_xor(s, 4, 8);
        out[(size_t)(b0 + b) * NCLS + n] = e / s;
    }
}

extern "C" void kernel_launch(void* const* d_in, const int* in_sizes, int n_in,
                              void* d_out, int out_size, void* d_ws, size_t ws_size,
                              hipStream_t stream) {
    const float* x     = (const float*)d_in[0];
    const float* Wih_f = (const float*)d_in[1];
    const float* Whh_f = (const float*)d_in[2];
    const float* bih_f = (const float*)d_in[3];
    const float* bhh_f = (const float*)d_in[4];
    const float* Wih_b = (const float*)d_in[5];
    // d_in[6] = Whh_b: unused — backward dir contributes only its first step (h0=0)
    const float* bih_b = (const float*)d_in[7];
    const float* bhh_b = (const float*)d_in[8];
    const float* fcW   = (const float*)d_in[9];
    const float* fcb   = (const float*)d_in[10];
    float* out = (float*)d_out;
    float* hf  = (float*)d_ws;   // 2048*64 fp32 = 512 KB scratch

    hipLaunchKernelGGL(lstm_fwd_mfma, dim3(2048 / BB), dim3(512), 0, stream,
                       x, Wih_f, Whh_f, bih_f, bhh_f, hf);
    hipLaunchKernelGGL(lstm_bwd_fc, dim3(2048 / B2), dim3(256), 0, stream,
                       x, Wih_b, bih_b, bhh_b, fcW, fcb, hf, out);
}

// Round 26
// 174.727 us; speedup vs baseline: 1.9230x; 1.9230x over previous
//
#include <hip/hip_runtime.h>
#include <math.h>

#define TT   256   // timesteps
#define HH   64    // hidden
#define INw  46    // input size
#define NCLS 8     // classes
#define BB   8     // batch rows per scan block (grid 256)
#define CH   4     // timesteps per chunk
#define NCH  (TT / CH)
#define B2   8     // batch rows per epilogue block
#define XS   80    // short stride for x/h LDS rows (160B -> 2-way free aliasing)

typedef __attribute__((ext_vector_type(8))) short  short8v;  // 8 bf16
typedef __attribute__((ext_vector_type(4))) float  float4v;

__device__ __forceinline__ float frcp(float x) { return __builtin_amdgcn_rcpf(x); }
__device__ __forceinline__ float sigmoid_f(float x) { return frcp(1.f + __expf(-x)); }
__device__ __forceinline__ float tanh_f(float x) {
    float a = fabsf(x);
    float e = __expf(-2.f * a);
    float r = (1.f - e) * frcp(1.f + e);
    return x >= 0.f ? r : -r;
}
__device__ __forceinline__ float dot4(float4 w, float4 a, float acc) {
    acc = fmaf(w.x, a.x, acc);
    acc = fmaf(w.y, a.y, acc);
    acc = fmaf(w.z, a.z, acc);
    acc = fmaf(w.w, a.w, acc);
    return acc;
}

// float -> bf16 round-to-nearest-even
__device__ __forceinline__ unsigned short f2bf(float f) {
    unsigned int u = __float_as_uint(f);
    unsigned int r = u + 0x7FFFu + ((u >> 16) & 1u);
    return (unsigned short)(r >> 16);
}
__device__ __forceinline__ float bf2f(unsigned short h) {
    return __uint_as_float(((unsigned int)h) << 16);
}
__device__ __forceinline__ void split8(const float v[8], short8v& hi, short8v& lo) {
#pragma unroll
    for (int e = 0; e < 8; ++e) {
        unsigned short h = f2bf(v[e]);
        hi[e] = (short)h;
        lo[e] = (short)f2bf(v[e] - bf2f(h));
    }
}

#define MFMA16(A,B,C) __builtin_amdgcn_mfma_f32_16x16x32_bf16((A),(B),(C),0,0,0)

// ---------------------------------------------------------------------------
// In-lane MFMA LSTM scan, ONE barrier per step (R23 — the session's best
// measured configuration; restored after R24/R25 co-residency attempts both
// spilled: consumer union register demand (~64 VGPR of Whh fragments + accs
// + state ~ 140-150 combined) exceeds the 128-cap of the 4-wave/SIMD bucket,
// so 2-block co-residency and the 1-barrier in-lane structure are mutually
// exclusive on this register file).
//   waves 0-3 (C): ALL four gate tiles of 16 units in-lane -> 24 MFMA/step,
//                  aliased-lane split (each g-group owns 2 batch rows:
//                  g0->0,1  g2->2,3  g1->4,5  g3->6,7), 8+2 transcendentals,
//                  cell update, h hi+lo write. NO cross-wave exchange.
//   waves 4-11 (P): two gate-pair groups (pg = w>=8); schedule: s0 stage-
//                  write x[c+1], s1 burst0, s2 burst1, s3 issue loads x[c+2].
// Single end-of-step barrier orders: h (opposite parities within a step),
// zx (read cb / write nb disjoint), x (s0 write vs s1/s2 reads separated).
// 3-term split-bf16, fp32 accumulate. 12 waves (3/SIMD), LDS ~79 KB.
// ---------------------------------------------------------------------------
__global__ __launch_bounds__(768, 3) void lstm_fwd_mfma(
    const float* __restrict__ x,     // (B,T,46)
    const float* __restrict__ Wih,   // (256,46)
    const float* __restrict__ Whh,   // (256,64)
    const float* __restrict__ bih,   // (256)
    const float* __restrict__ bhh,   // (256)
    float* __restrict__ hf_out)      // (B,64)
{
    __shared__ float zx[2][CH][4][HH][8];    // 64 KB (chunk-parity dbuf)
    __shared__ short x_hi[CH][BB][XS];       // 5 KB  (single buffer)
    __shared__ short x_lo[CH][BB][XS];       // 5 KB
    __shared__ short h_hi[2][BB][XS];        // 2.5 KB (step-parity dbuf)
    __shared__ short h_lo[2][BB][XS];        // 2.5 KB

    const int j    = threadIdx.x;
    const int w    = j >> 6;
    const int l    = j & 63;
    const int g    = l >> 4;
    const int c16  = l & 15;
    const int b0   = blockIdx.x * BB;
    const int wl   = w & 3;
    const int u    = 16 * wl + c16;
    const int r0p  = ((g & 1) * 4) ^ (u & 4);
    const bool isC  = (w < 4);
    const bool isP  = !isC;
    const int  pg   = (w >= 8) ? 1 : 0;      // producer gate-pair group
    // aliased-lane split: this lane's 2 batch rows and matching C-reg offset
    const bool hi2  = (g & 2) != 0;          // use regs 2,3 instead of 0,1
    const int  row0 = 4 * (g & 1) + 2 * (g >> 1);   // first owned batch row

    // ---- weight fragments ----
    // consumers: wf[q]=Whh_hi, wf[4+q]=Whh_lo for gate q = 0..3
    // producers: wf[qq]=Wih_hi, wf[2+qq]=Wih_lo for gates q = 2*pg+qq
    short8v wf[8][2];
    float bias4[4] = {0.f, 0.f, 0.f, 0.f};
    if (isC) {
#pragma unroll
        for (int q = 0; q < 4; ++q) {
            const int n = 64 * q + u;
            bias4[q] = bih[n] + bhh[n];
#pragma unroll
            for (int s2 = 0; s2 < 2; ++s2) {
                float vh[8];
#pragma unroll
                for (int e = 0; e < 8; ++e)
                    vh[e] = Whh[n * HH + 32 * s2 + 8 * g + e];
                split8(vh, wf[q][s2], wf[4 + q][s2]);
            }
        }
    } else {
#pragma unroll
        for (int qq = 0; qq < 2; ++qq) {
            const int n = 64 * (2 * pg + qq) + u;
#pragma unroll
            for (int s2 = 0; s2 < 2; ++s2) {
                float vi[8];
#pragma unroll
                for (int e = 0; e < 8; ++e) {
                    const int k = 32 * s2 + 8 * g + e;
                    const float tval = Wih[n * INw + ((k < INw) ? k : 0)];
                    vi[e] = (k < INw) ? tval : 0.f;
                }
                split8(vi, wf[qq][s2], wf[2 + qq][s2]);
            }
        }
    }

    // ---- zero h bufs and x bufs (incl. k>=46 pad; staging writes only k<46,
    //      pad stays zero across all chunks) ----
    {
        short* hh0 = &h_hi[0][0][0];
        short* hl0 = &h_lo[0][0][0];
        for (int idx = j; idx < 2 * BB * XS; idx += 768) {
            hh0[idx] = 0;
            hl0[idx] = 0;
        }
        short* xh0 = &x_hi[0][0][0];
        short* xl0 = &x_lo[0][0][0];
        for (int idx = j; idx < CH * BB * XS; idx += 768) {
            xh0[idx] = 0;
            xl0[idx] = 0;
        }
    }
    __syncthreads();

    // ---- stage x chunk 0 (all threads) ----
    for (int e = j; e < BB * CH * INw; e += 768) {
        const int r   = e / (CH * INw);
        const int rem = e - r * (CH * INw);
        const int tt  = rem / INw;
        const int k   = rem - tt * INw;
        const float v = x[((size_t)(b0 + r) * TT + tt) * INw + k];
        const unsigned short hh = f2bf(v);
        x_hi[tt][r][k] = (short)hh;
        x_lo[tt][r][k] = (short)f2bf(v - bf2f(hh));
    }
    __syncthreads();

    // zx producer burst: this group's 2 gates (q = 2*pg + qq)
    auto zx_burst = [&](int tau, int nbuf) {
        const int trel = 2 * tau + (c16 >> 3);
        const int rr   = c16 & 7;
        const short* ph = &x_hi[trel][rr][0] + 8 * g;
        const short* pl = &x_lo[trel][rr][0] + 8 * g;
        const short8v axh0 = *(const short8v*)(ph);
        const short8v axh1 = *(const short8v*)(ph + 32);
        const short8v axl0 = *(const short8v*)(pl);
        const short8v axl1 = *(const short8v*)(pl + 32);
        const int tout = 2 * tau + (g >> 1);
#pragma unroll
        for (int qq = 0; qq < 2; ++qq) {
            const int q = 2 * pg + qq;
            float4v C = {0.f, 0.f, 0.f, 0.f};
            C = MFMA16(axh0, wf[qq][0], C);
            C = MFMA16(axh1, wf[qq][1], C);
            C = MFMA16(axh0, wf[2 + qq][0], C);
            C = MFMA16(axh1, wf[2 + qq][1], C);
            C = MFMA16(axl0, wf[qq][0], C);
            C = MFMA16(axl1, wf[qq][1], C);
            *(float4v*)&zx[nbuf][tout][q][u][r0p] = C;
        }
    };

    // staging offsets (P lanes: j-256 in [0,512); 1472 elems -> 3 slots)
    size_t st_gof[3]; int st_lds[3]; bool st_ok[3];
#pragma unroll
    for (int it = 0; it < 3; ++it) {
        const int e  = (j - 256) + 512 * it;
        const bool ok = (e >= 0) && (e < BB * CH * INw);
        const int ec = ok ? e : 0;
        const int r   = ec / (CH * INw);
        const int rem = ec - r * (CH * INw);
        const int tt  = rem / INw;
        const int k   = rem - tt * INw;
        st_ok[it]  = ok;
        st_gof[it] = ((size_t)(b0 + r) * TT + tt) * INw + k;
        st_lds[it] = (tt * BB + r) * XS + k;
    }
    short* xsh = &x_hi[0][0][0];
    short* xsl = &x_lo[0][0][0];

    // ---- prologue: zx[0] (producers) + issue global loads for chunk 1 ----
    float xhold[3];
    if (isP) {
        zx_burst(0, 0);
        zx_burst(1, 0);
#pragma unroll
        for (int it = 0; it < 3; ++it)
            if (st_ok[it]) xhold[it] = x[st_gof[it] + (size_t)(CH * INw)];
    }

    float cst2[2]  = {0.f, 0.f};   // cell state for this lane's 2 rows
    float hnew2[2] = {0.f, 0.f};
    __syncthreads();

    for (int c = 0; c < NCH; ++c) {
        const int cb = c & 1, nb = cb ^ 1;
#pragma unroll
        for (int s = 0; s < CH; ++s) {
            const int t = c * CH + s;
            // ============ single phase: all work, then ONE barrier =========
            if (isC) {
                const short* hrh = &h_hi[(t + 1) & 1][0][0];
                const short* hrl = &h_lo[(t + 1) & 1][0][0];
                const int ro = (c16 & 7) * XS;
                const short8v ahh0 = *(const short8v*)(hrh + ro + 8 * g);
                const short8v ahh1 = *(const short8v*)(hrh + ro + 32 + 8 * g);
                const short8v ahl0 = *(const short8v*)(hrl + ro + 8 * g);
                const short8v ahl1 = *(const short8v*)(hrl + ro + 32 + 8 * g);
                const float* zr = &zx[cb][s][0][u][r0p];
                float4v C0 = *(const float4v*)(zr);
                float4v C1 = *(const float4v*)(zr + 512);
                float4v C2 = *(const float4v*)(zr + 1024);
                float4v C3 = *(const float4v*)(zr + 1536);
                float4v D0 = {0.f, 0.f, 0.f, 0.f};
                float4v D1 = {0.f, 0.f, 0.f, 0.f};
                __builtin_amdgcn_s_setprio(1);
                // gates 0,1 (i,f)
                C0 = MFMA16(ahh0, wf[0][0], C0);
                C1 = MFMA16(ahh0, wf[1][0], C1);
                D0 = MFMA16(ahl0, wf[0][0], D0);
                D1 = MFMA16(ahl0, wf[1][0], D1);
                C0 = MFMA16(ahh1, wf[0][1], C0);
                C1 = MFMA16(ahh1, wf[1][1], C1);
                D0 = MFMA16(ahl1, wf[0][1], D0);
                D1 = MFMA16(ahl1, wf[1][1], D1);
                D0 = MFMA16(ahh0, wf[4][0], D0);
                D1 = MFMA16(ahh0, wf[5][0], D1);
                D0 = MFMA16(ahh1, wf[4][1], D0);
                D1 = MFMA16(ahh1, wf[5][1], D1);
                C0 += D0;
                C1 += D1;
                // gates 2,3 (g,o)
                float4v E0 = {0.f, 0.f, 0.f, 0.f};
                float4v E1 = {0.f, 0.f, 0.f, 0.f};
                C2 = MFMA16(ahh0, wf[2][0], C2);
                C3 = MFMA16(ahh0, wf[3][0], C3);
                E0 = MFMA16(ahl0, wf[2][0], E0);
                E1 = MFMA16(ahl0, wf[3][0], E1);
                C2 = MFMA16(ahh1, wf[2][1], C2);
                C3 = MFMA16(ahh1, wf[3][1], C3);
                E0 = MFMA16(ahl1, wf[2][1], E0);
                E1 = MFMA16(ahl1, wf[3][1], E1);
                E0 = MFMA16(ahh0, wf[6][0], E0);
                E1 = MFMA16(ahh0, wf[7][0], E1);
                E0 = MFMA16(ahh1, wf[6][1], E0);
                E1 = MFMA16(ahh1, wf[7][1], E1);
                __builtin_amdgcn_s_setprio(0);
                C2 += E0;
                C3 += E1;
                // in-lane update for MY 2 rows
                const int ri = hi2 ? 2 : 0;
#pragma unroll
                for (int rr = 0; rr < 2; ++rr) {
                    const float iv = sigmoid_f(C0[ri + rr] + bias4[0]);
                    const float fv = sigmoid_f(C1[ri + rr] + bias4[1]);
                    const float gv = tanh_f   (C2[ri + rr] + bias4[2]);
                    const float ov = sigmoid_f(C3[ri + rr] + bias4[3]);
                    cst2[rr]  = fmaf(fv, cst2[rr], iv * gv);
                    hnew2[rr] = ov * tanh_f(cst2[rr]);
                }
                short* hwh = &h_hi[t & 1][0][0] + row0 * XS + u;
                short* hwl = &h_lo[t & 1][0][0] + row0 * XS + u;
                const unsigned short h0h = f2bf(hnew2[0]);
                hwh[0]  = (short)h0h;
                hwl[0]  = (short)f2bf(hnew2[0] - bf2f(h0h));
                const unsigned short h1h = f2bf(hnew2[1]);
                hwh[XS] = (short)h1h;
                hwl[XS] = (short)f2bf(hnew2[1] - bf2f(h1h));
            } else {
                if (s == 0 && c + 1 < NCH) {
                    // write held x for chunk c+1 (loads issued at (c-1, s3))
#pragma unroll
                    for (int it = 0; it < 3; ++it) {
                        if (st_ok[it]) {
                            const unsigned short hh = f2bf(xhold[it]);
                            xsh[st_lds[it]] = (short)hh;
                            xsl[st_lds[it]] = (short)f2bf(xhold[it] - bf2f(hh));
                        }
                    }
                } else if (s == 1 && c + 1 < NCH) {
                    zx_burst(0, nb);
                } else if (s == 2 && c + 1 < NCH) {
                    zx_burst(1, nb);
                } else if (s == 3 && c + 2 < NCH) {
                    const size_t cofs = (size_t)(c + 2) * (CH * INw);
#pragma unroll
                    for (int it = 0; it < 3; ++it)
                        if (st_ok[it]) xhold[it] = x[st_gof[it] + cofs];
                }
            }
            __syncthreads();   // THE one barrier per step
        }
    }

    if (isC) {
        hf_out[(size_t)(b0 + row0)     * HH + u] = hnew2[0];
        hf_out[(size_t)(b0 + row0 + 1) * HH + u] = hnew2[1];
    }
}

// ---------------------------------------------------------------------------
// Epilogue: backward dir = ONE LSTM step on x[:,T-1,:] (h0=c0=0, Whh_b unused),
// then FC + softmax.
// ---------------------------------------------------------------------------
__global__ __launch_bounds__(256) void lstm_bwd_fc(
    const float* __restrict__ x,
    const float* __restrict__ Wih,
    const float* __restrict__ bih,
    const float* __restrict__ bhh,
    const float* __restrict__ fcW,
    const float* __restrict__ fcb,
    const float* __restrict__ hf,
    float* __restrict__ out)
{
    __shared__ float xl[B2][48];
    __shared__ float act[B2][256];
    __shared__ float hbl[B2][HH];

    const int j  = threadIdx.x;
    const int b0 = blockIdx.x * B2;

    for (int e = j; e < B2 * INw; e += 256) {
        int b = e / INw, i = e - b * INw;
        xl[b][i] = x[((size_t)(b0 + b) * TT + (TT - 1)) * INw + i];
    }
    if (j < B2) { xl[j][46] = 0.f; xl[j][47] = 0.f; }
    __syncthreads();

    float4 wih4[12];
#pragma unroll
    for (int ii = 0; ii < 11; ++ii)
        wih4[ii] = make_float4(Wih[j*INw + 4*ii + 0], Wih[j*INw + 4*ii + 1],
                               Wih[j*INw + 4*ii + 2], Wih[j*INw + 4*ii + 3]);
    wih4[11] = make_float4(Wih[j*INw + 44], Wih[j*INw + 45], 0.f, 0.f);
    const float bias = bih[j] + bhh[j];
    const bool  gate_is_tanh = ((j >> 6) == 2);

#pragma unroll
    for (int b = 0; b < B2; ++b) {
        float a = bias;
#pragma unroll
        for (int ii = 0; ii < 12; ++ii) {
            float4 xv = *(const float4*)&xl[b][4*ii];
            a = dot4(wih4[ii], xv, a);
        }
        act[b][j] = gate_is_tanh ? tanh_f(a) : sigmoid_f(a);
    }
    __syncthreads();

    for (int q = j; q < B2 * HH; q += 256) {
        int b = q >> 6, ll = q & 63;
        float ig = act[b][ll];
        float gg = act[b][128 + ll];
        float og = act[b][192 + ll];
        hbl[b][ll] = og * tanh_f(ig * gg);
    }
    __syncthreads();

    if (j < B2 * NCLS) {
        int b = j >> 3, n = j & 7;
        float a = fcb[n];
        const float* hfr = hf + (size_t)(b0 + b) * HH;
#pragma unroll
        for (int ll = 0; ll < HH; ++ll) {
            a = fmaf(fcW[n * 2 * HH + ll],      hfr[ll],    a);
            a = fmaf(fcW[n * 2 * HH + HH + ll], hbl[b][ll], a);
        }
        float m = a;
        m = fmaxf(m, __shfl_xor(m, 1, 8));
        m = fmaxf(m, __shfl_xor(m, 2, 8));
        m = fmaxf(m, __shfl_xor(m, 4, 8));
        float e = __expf(a - m);
        float s = e;
        s += __shfl_xor(s, 1, 8);
        s += __shfl_xor(s, 2, 8);
        s += __shfl_xor(s, 4, 8);
        out[(size_t)(b0 + b) * NCLS + n] = e / s;
    }
}

extern "C" void kernel_launch(void* const* d_in, const int* in_sizes, int n_in,
                              void* d_out, int out_size, void* d_ws, size_t ws_size,
                              hipStream_t stream) {
    const float* x     = (const float*)d_in[0];
    const float* Wih_f = (const float*)d_in[1];
    const float* Whh_f = (const float*)d_in[2];
    const float* bih_f = (const float*)d_in[3];
    const float* bhh_f = (const float*)d_in[4];
    const float* Wih_b = (const float*)d_in[5];
    // d_in[6] = Whh_b: unused — backward dir contributes only its first step (h0=0)
    const float* bih_b = (const float*)d_in[7];
    const float* bhh_b = (const float*)d_in[8];
    const float* fcW   = (const float*)d_in[9];
    const float* fcb   = (const float*)d_in[10];
    float* out = (float*)d_out;
    float* hf  = (float*)d_ws;   // 2048*64 fp32 = 512 KB scratch

    hipLaunchKernelGGL(lstm_fwd_mfma, dim3(2048 / BB), dim3(768), 0, stream,
                       x, Wih_f, Whh_f, bih_f, bhh_f, hf);
    hipLaunchKernelGGL(lstm_bwd_fc, dim3(2048 / B2), dim3(256), 0, stream,
                       x, Wih_b, bih_b, bhh_b, fcW, fcb, hf, out);
}